// Round 1
// baseline (728.569 us; speedup 1.0000x reference)
//
#include <hip/hip_runtime.h>
#include <stdint.h>

typedef __attribute__((ext_vector_type(8))) short short8;
typedef __attribute__((ext_vector_type(4))) float float4v;

#define NPIX 240
#define PIXSTRIDE 72   // shorts per pixel (64 ci + 8 pad) = 144 B, 16B aligned

// ws layout: [0, 57344): wsA frag-ordered bf16 weights (4ct*14ks*64lane*8)
//            [57344, 58244): map (225 int)  (padded to 58256)
//            [58256, 58932): out-mask (169 float)
#define WSA_BYTES 57344
#define MAP_OFF   57344
#define OM_OFF    58256

__device__ __forceinline__ unsigned short f2bf(float f) {
    union { float f; unsigned u; } v; v.f = f;
    unsigned r = v.u + 0x7FFFu + ((v.u >> 16) & 1u);   // RNE
    return (unsigned short)(r >> 16);
}

__global__ void hex_prep_kernel(const float* __restrict__ w,
                                unsigned short* __restrict__ wsA,
                                int* __restrict__ map,
                                float* __restrict__ om) {
    const int tid = threadIdx.x;
    const int ti_tab[7] = {0,0,1,1,1,2,2};
    const int tj_tab[7] = {0,1,0,1,2,1,2};
    // fragment-ordered weights: item = (ct*14 + ks)*64 + lane, 8 bf16 each
    for (int item = tid; item < 4*14*64; item += blockDim.x) {
        int lane = item & 63;
        int ks   = (item >> 6) % 14;
        int ct   = (item >> 6) / 14;
        int co = ct*16 + (lane & 15);
        int k0 = ks*32 + (lane >> 4)*8;
        unsigned short vals[8];
        #pragma unroll
        for (int j = 0; j < 8; ++j) {
            int k = k0 + j;
            int tap = k >> 6, ci = k & 63;
            float v = w[(co*64 + ci)*9 + ti_tab[tap]*3 + tj_tab[tap]];
            vals[j] = f2bf(v);
        }
        for (int j = 0; j < 8; ++j) wsA[item*8 + j] = vals[j];
    }
    if (tid == 0) {
        // hex padding source map: replay reference copies on indices
        int m[225];
        for (int r = 0; r < 15; ++r)
            for (int c = 0; c < 15; ++c)
                m[r*15+c] = (r>=1 && r<=13 && c>=1 && c<=13) ? (r-1)*13 + (c-1) : -1;
        #define M(r,c) m[(r)*15+(c)]
        for (int t = 0; t < 7; ++t) M(0,1+t)    = M(12,7+t);
        for (int r = 0; r < 3; ++r) M(r,8+r)    = M(6+r,2+r);
        for (int r = 0; r < 4; ++r) M(3+r,10+r) = M(9+r,4+r);
        for (int r = 0; r < 3; ++r) M(7+r,13)   = M(1+r,1);
        for (int r = 0; r < 3; ++r) M(10+r,14)  = M(4+r,2);
        for (int r = 0; r < 8; ++r) M(13,7+r)   = M(1,1+r);
        for (int r = 0; r < 4; ++r) M(9+r,3+r)  = M(3+r,9+r);
        for (int r = 0; r < 3; ++r) M(6+r,1+r)  = M(r,7+r);
        for (int r = 0; r < 2; ++r) M(4+r,1)    = M(10+r,13);
        for (int r = 0; r < 4; ++r) M(r,0)      = M(6+r,12);
        #undef M
        for (int i = 0; i < 225; ++i) map[i] = m[i];
        // output mask
        float o[169];
        for (int i = 0; i < 169; ++i) o[i] = 1.f;
        for (int i = 0; i < 5; ++i) for (int j = 8+i; j < 13; ++j) o[i*13+j] = 0.f;
        for (int i = 0; i < 4; ++i) o[(2+i)*13 + 9+i] = 0.f;
        for (int i = 6; i < 9; ++i) o[i*13 + 12] = 0.f;
        for (int i = 0; i < 6; ++i) for (int j = 0; j <= i; ++j) o[(6+i)*13 + j] = 0.f;
        for (int i = 0; i < 3; ++i) o[(5+i)*13 + i] = 0.f;
        o[3*13 + 0] = 0.f; o[4*13 + 0] = 0.f;
        for (int i = 0; i < 169; ++i) om[i] = o[i];
    }
}

__global__ __launch_bounds__(256) void hexconv_kernel(
        const float* __restrict__ x, const float* __restrict__ bias,
        const unsigned short* __restrict__ wsA, const int* __restrict__ map,
        const float* __restrict__ om, float* __restrict__ out) {
    __shared__ unsigned short Xs[NPIX * PIXSTRIDE];
    const int b   = blockIdx.x;
    const int tid = threadIdx.x;
    const float* xb = x + (size_t)b * 64 * 169;

    // stage: Xs[pix][ci] = hex-padded image, channel-last, bf16
    for (int e = tid; e < NPIX*64; e += 256) {
        int pix = e % NPIX;
        int ci  = e / NPIX;
        int sp  = (pix < 225) ? map[pix] : -1;
        float v = (sp >= 0) ? xb[ci*169 + sp] : 0.f;
        Xs[pix*PIXSTRIDE + ci] = f2bf(v);
    }
    __syncthreads();

    const int wave = tid >> 6, lane = tid & 63;
    const int lr = lane & 15;   // within-tile col (N=pos) / A-row select
    const int lq = lane >> 4;   // quad

    float4v acc[4][4];
    #pragma unroll
    for (int ct = 0; ct < 4; ++ct)
        #pragma unroll
        for (int i = 0; i < 4; ++i)
            acc[ct][i] = float4v{0.f, 0.f, 0.f, 0.f};

    #pragma unroll
    for (int ks = 0; ks < 14; ++ks) {
        // A fragments for all 4 co-tiles: coalesced 16B/lane from frag-ordered table
        short8 afr[4];
        #pragma unroll
        for (int ct = 0; ct < 4; ++ct)
            afr[ct] = *(const short8*)(wsA + (size_t)((ct*14 + ks)*64 + lane)*8);
        const int tap  = ks >> 1;                       // k-step never straddles a tap
        const int cib  = (ks & 1)*32 + lq*8;            // ci base for this lane's 8 k's
        const int offs[7] = {0,1,15,16,17,31,32};       // ti*15+tj for the 7 hex taps
        const int pixb = lr + offs[tap];
        #pragma unroll
        for (int i = 0; i < 4; ++i) {
            int nt = wave + i*4;
            if (nt < 13) {
                short8 bfr = *(const short8*)(&Xs[(nt*16 + pixb)*PIXSTRIDE + cib]);
                #pragma unroll
                for (int ct = 0; ct < 4; ++ct)
                    acc[ct][i] = __builtin_amdgcn_mfma_f32_16x16x32_bf16(
                        afr[ct], bfr, acc[ct][i], 0, 0, 0);
            }
        }
    }

    // epilogue: C row = co = ct*16 + lq*4 + r, col = p15 = nt*16 + lr
    #pragma unroll
    for (int i = 0; i < 4; ++i) {
        int nt = wave + i*4;
        if (nt >= 13) continue;
        int p15  = nt*16 + lr;
        int y    = p15 / 15, xcol = p15 % 15;
        bool valid = (xcol < 13) & (y < 13);
        float omv = valid ? om[y*13 + xcol] : 0.f;
        #pragma unroll
        for (int ct = 0; ct < 4; ++ct) {
            #pragma unroll
            for (int r = 0; r < 4; ++r) {
                int co = ct*16 + lq*4 + r;
                if (valid) {
                    float v = (acc[ct][i][r] + bias[co]) * omv;
                    out[((size_t)b*64 + co)*169 + y*13 + xcol] = v;
                }
            }
        }
    }
}

extern "C" void kernel_launch(void* const* d_in, const int* in_sizes, int n_in,
                              void* d_out, int out_size, void* d_ws, size_t ws_size,
                              hipStream_t stream) {
    const float* x    = (const float*)d_in[0];
    const float* w    = (const float*)d_in[1];
    const float* bias = (const float*)d_in[2];
    float* out = (float*)d_out;

    unsigned short* wsA = (unsigned short*)d_ws;
    int*   map = (int*)((char*)d_ws + MAP_OFF);
    float* om  = (float*)((char*)d_ws + OM_OFF);

    hex_prep_kernel<<<1, 256, 0, stream>>>(w, wsA, map, om);

    int B = in_sizes[0] / (64 * 169);   // 4096 images
    hexconv_kernel<<<B, 256, 0, stream>>>(x, bias, wsA, map, om, out);
}

// Round 2
// 358.420 us; speedup vs baseline: 2.0327x; 2.0327x over previous
//
#include <hip/hip_runtime.h>
#include <stdint.h>

typedef __attribute__((ext_vector_type(8))) short short8;
typedef __attribute__((ext_vector_type(4))) float float4v;

#define NPIX 240
#define PIXSTRIDE 68   // shorts per pixel (64 ci + 4 pad) = 136 B: 8B-aligned rows,
                       // word-stride 34 == 2 mod 32 -> 2-way (free) write conflicts

// ws layout: [0, 57344): wsA frag-ordered bf16 weights (4ct*14ks*64lane*8)
//            [57344, 58304): map (240 int, last 15 = -1)
//            [58304, 58980): out-mask (169 float)
#define MAP_OFF   57344
#define OM_OFF    58304

__device__ __forceinline__ unsigned short f2bf(float f) {
    union { float f; unsigned u; } v; v.f = f;
    unsigned r = v.u + 0x7FFFu + ((v.u >> 16) & 1u);   // RNE
    return (unsigned short)(r >> 16);
}

__global__ void hex_prep_kernel(const float* __restrict__ w,
                                unsigned short* __restrict__ wsA,
                                int* __restrict__ map,
                                float* __restrict__ om) {
    const int gid = blockIdx.x * blockDim.x + threadIdx.x;
    const int nthr = gridDim.x * blockDim.x;
    const int ti_tab[7] = {0,0,1,1,1,2,2};
    const int tj_tab[7] = {0,1,0,1,2,1,2};
    // fragment-ordered weights: item = (ct*14 + ks)*64 + lane, 8 bf16 each
    for (int item = gid; item < 4*14*64; item += nthr) {
        int lane = item & 63;
        int ks   = (item >> 6) % 14;
        int ct   = (item >> 6) / 14;
        int co = ct*16 + (lane & 15);
        int k0 = ks*32 + (lane >> 4)*8;
        unsigned short vals[8];
        #pragma unroll
        for (int j = 0; j < 8; ++j) {
            int k = k0 + j;
            int tap = k >> 6, ci = k & 63;
            vals[j] = f2bf(w[(co*64 + ci)*9 + ti_tab[tap]*3 + tj_tab[tap]]);
        }
        for (int j = 0; j < 8; ++j) wsA[item*8 + j] = vals[j];
    }
    if (gid == 0) {
        // hex padding source map: replay reference copies on indices
        int m[225];
        for (int r = 0; r < 15; ++r)
            for (int c = 0; c < 15; ++c)
                m[r*15+c] = (r>=1 && r<=13 && c>=1 && c<=13) ? (r-1)*13 + (c-1) : -1;
        #define M(r,c) m[(r)*15+(c)]
        for (int t = 0; t < 7; ++t) M(0,1+t)    = M(12,7+t);
        for (int r = 0; r < 3; ++r) M(r,8+r)    = M(6+r,2+r);
        for (int r = 0; r < 4; ++r) M(3+r,10+r) = M(9+r,4+r);
        for (int r = 0; r < 3; ++r) M(7+r,13)   = M(1+r,1);
        for (int r = 0; r < 3; ++r) M(10+r,14)  = M(4+r,2);
        for (int r = 0; r < 8; ++r) M(13,7+r)   = M(1,1+r);
        for (int r = 0; r < 4; ++r) M(9+r,3+r)  = M(3+r,9+r);
        for (int r = 0; r < 3; ++r) M(6+r,1+r)  = M(r,7+r);
        for (int r = 0; r < 2; ++r) M(4+r,1)    = M(10+r,13);
        for (int r = 0; r < 4; ++r) M(r,0)      = M(6+r,12);
        #undef M
        for (int i = 0; i < 225; ++i) map[i] = m[i];
        for (int i = 225; i < 240; ++i) map[i] = -1;
        // output mask
        float o[169];
        for (int i = 0; i < 169; ++i) o[i] = 1.f;
        for (int i = 0; i < 5; ++i) for (int j = 8+i; j < 13; ++j) o[i*13+j] = 0.f;
        for (int i = 0; i < 4; ++i) o[(2+i)*13 + 9+i] = 0.f;
        for (int i = 6; i < 9; ++i) o[i*13 + 12] = 0.f;
        for (int i = 0; i < 6; ++i) for (int j = 0; j <= i; ++j) o[(6+i)*13 + j] = 0.f;
        for (int i = 0; i < 3; ++i) o[(5+i)*13 + i] = 0.f;
        o[3*13 + 0] = 0.f; o[4*13 + 0] = 0.f;
        for (int i = 0; i < 169; ++i) om[i] = o[i];
    }
}

// wave w: ctp = w&1 owns co-tiles {2ctp, 2ctp+1}; nth = w>>1 owns nt = nth*7 + j.
// All A-fragments preloaded to regs (112 VGPR) before staging -> zero global
// loads in the MFMA loop.
__global__ __launch_bounds__(256, 2) void hexconv_kernel(
        const float* __restrict__ x, const float* __restrict__ bias,
        const unsigned short* __restrict__ wsA, const int* __restrict__ map,
        const float* __restrict__ om, float* __restrict__ out) {
    __shared__ unsigned short Xs[NPIX * PIXSTRIDE];
    const int b   = blockIdx.x;
    const int tid = threadIdx.x;
    const int lane = tid & 63, wv = tid >> 6;
    const int lr = lane & 15, lq = lane >> 4;
    const float* xb = x + (size_t)b * 64 * 169;

    const int ctp = wv & 1;
    const int nth = wv >> 1;

    // ---- A-frag preload (issued first; latency hides behind staging) ----
    short8 afr[2][14];
    #pragma unroll
    for (int c = 0; c < 2; ++c) {
        const int ct = ctp*2 + c;
        #pragma unroll
        for (int ks = 0; ks < 14; ++ks)
            afr[c][ks] = *(const short8*)(wsA + (size_t)((ct*14 + ks)*64 + lane)*8);
    }

    // ---- staging: lane <-> pixel, wave <-> ci-block; no load->load chains ----
    int sp[4];
    #pragma unroll
    for (int pi = 0; pi < 4; ++pi) {
        int pix = lane + 64*pi;
        sp[pi] = (pix < NPIX) ? map[pix] : -1;
    }
    #pragma unroll
    for (int pi = 0; pi < 4; ++pi) {
        int pix = lane + 64*pi;
        if (pix < NPIX) {
            const int s = sp[pi];
            unsigned short vals[16];
            #pragma unroll
            for (int cj = 0; cj < 16; ++cj) {
                int ci = wv*16 + cj;
                float v = (s >= 0) ? xb[ci*169 + s] : 0.f;
                vals[cj] = f2bf(v);
            }
            #pragma unroll
            for (int q = 0; q < 4; ++q) {
                uint64_t pk = (uint64_t)vals[4*q]
                            | ((uint64_t)vals[4*q+1] << 16)
                            | ((uint64_t)vals[4*q+2] << 32)
                            | ((uint64_t)vals[4*q+3] << 48);
                *(uint64_t*)&Xs[pix*PIXSTRIDE + wv*16 + q*4] = pk;
            }
        }
    }
    __syncthreads();

    // ---- main loop: pure LDS + MFMA ----
    float4v acc[2][7];
    #pragma unroll
    for (int c = 0; c < 2; ++c)
        #pragma unroll
        for (int j = 0; j < 7; ++j)
            acc[c][j] = float4v{0.f, 0.f, 0.f, 0.f};

    const int offs[7] = {0,1,15,16,17,31,32};   // ti*15+tj for the 7 hex taps
    #pragma unroll
    for (int ks = 0; ks < 14; ++ks) {
        const int tap = ks >> 1;                 // k-step never straddles a tap
        const int cib = (ks & 1)*32 + lq*8;
        #pragma unroll
        for (int j = 0; j < 7; ++j) {
            int nt = nth*7 + j;
            if (nt < 13) {
                int pixb = nt*16 + lr + offs[tap];
                const unsigned short* p = &Xs[pixb*PIXSTRIDE + cib];
                union { short8 v; uint64_t q[2]; } u;
                u.q[0] = *(const uint64_t*)p;
                u.q[1] = *(const uint64_t*)(p + 4);
                #pragma unroll
                for (int c = 0; c < 2; ++c)
                    acc[c][j] = __builtin_amdgcn_mfma_f32_16x16x32_bf16(
                        afr[c][ks], u.v, acc[c][j], 0, 0, 0);
            }
        }
    }

    // ---- epilogue: row co = ct*16 + lq*4 + r, col p15 = nt*16 + lr ----
    #pragma unroll
    for (int j = 0; j < 7; ++j) {
        int nt = nth*7 + j;
        if (nt >= 13) continue;
        int p15 = nt*16 + lr;
        int y = p15 / 15, xc = p15 % 15;
        if (xc >= 13 || y >= 13) continue;
        float omv = om[y*13 + xc];
        size_t obase = (size_t)b*64*169 + y*13 + xc;
        #pragma unroll
        for (int c = 0; c < 2; ++c) {
            int ct = ctp*2 + c;
            #pragma unroll
            for (int r = 0; r < 4; ++r) {
                int co = ct*16 + lq*4 + r;
                out[obase + (size_t)co*169] = (acc[c][j][r] + bias[co]) * omv;
            }
        }
    }
}

extern "C" void kernel_launch(void* const* d_in, const int* in_sizes, int n_in,
                              void* d_out, int out_size, void* d_ws, size_t ws_size,
                              hipStream_t stream) {
    const float* x    = (const float*)d_in[0];
    const float* w    = (const float*)d_in[1];
    const float* bias = (const float*)d_in[2];
    float* out = (float*)d_out;

    unsigned short* wsA = (unsigned short*)d_ws;
    int*   map = (int*)((char*)d_ws + MAP_OFF);
    float* om  = (float*)((char*)d_ws + OM_OFF);

    hex_prep_kernel<<<16, 256, 0, stream>>>(w, wsA, map, om);

    int B = in_sizes[0] / (64 * 169);   // 4096 images
    hexconv_kernel<<<B, 256, 0, stream>>>(x, bias, wsA, map, om, out);
}